// Round 1
// baseline (4631.903 us; speedup 1.0000x reference)
//
#include <hip/hip_runtime.h>
#include <math.h>

// ssp(x) = softplus(x) - log(2)
__device__ __forceinline__ float ssp(float x) {
    float sp = (x > 20.0f) ? x : log1pf(expf(x));
    return sp - 0.69314718055994530942f;
}

// ---------------------------------------------------------------------------
// Scatter-add: acc[tgt[edge]] += e[edge]   (one thread per float4 of e)
// ---------------------------------------------------------------------------
__global__ __launch_bounds__(256) void scatter_kernel(
    const float* __restrict__ e, const int* __restrict__ tgt,
    float* __restrict__ acc, long long total4)
{
    long long i = (long long)blockIdx.x * 256 + threadIdx.x;
    if (i >= total4) return;
    int edge = (int)(i >> 5);     // 32 float4 per 128-float row
    int c4   = (int)(i & 31);
    int node = tgt[edge];
    float4 val = ((const float4*)e)[i];
    float* p = acc + (long long)node * 128 + c4 * 4;
    unsafeAtomicAdd(p + 0, val.x);
    unsafeAtomicAdd(p + 1, val.y);
    unsafeAtomicAdd(p + 2, val.z);
    unsafeAtomicAdd(p + 3, val.w);
}

// ---------------------------------------------------------------------------
// Fused MLP: per 16-node tile:
//   zm = W2 * ssp(W1*xm + b1) + b2
//   zh = W2h * ssp(W1h*xh + b1h) + b2h
//   out = v + ssp(Wc * cat(zm, zh) + bc)
// Block = 256 threads: thread (n = tid&15, oc = tid>>4) computes 8 output
// channels [oc*8, oc*8+8) for node n. LDS rows padded to 132 floats
// (132*4 = 528 bytes, 16B-aligned; lane-bank aliasing is 2-way = free).
// ---------------------------------------------------------------------------
#define PAD 132

__global__ __launch_bounds__(256) void mlp_kernel(
    const float* __restrict__ accm, const float* __restrict__ acch,
    const float* __restrict__ v,
    const float* __restrict__ W1,  const float* __restrict__ b1,
    const float* __restrict__ W2,  const float* __restrict__ b2,
    const float* __restrict__ W1h, const float* __restrict__ b1h,
    const float* __restrict__ W2h, const float* __restrict__ b2h,
    const float* __restrict__ Wc,  const float* __restrict__ bc,
    float* __restrict__ out, int n_nodes)
{
    __shared__ float xm[16 * PAD];
    __shared__ float xh[16 * PAD];
    __shared__ float ym[16 * PAD];
    __shared__ float yh[16 * PAD];

    const int tid = threadIdx.x;
    const int ln  = tid & 15;    // node within tile
    const int oc  = tid >> 4;    // output-channel chunk (0..15)
    const int o0  = oc * 8;
    const int node0 = blockIdx.x * 16;

    // ---- stage the two accumulator tiles into LDS (512 float4 each) ----
    for (int p = tid; p < 512; p += 256) {
        int r = p >> 5, c = p & 31;
        float4 a = make_float4(0.f, 0.f, 0.f, 0.f);
        float4 b = make_float4(0.f, 0.f, 0.f, 0.f);
        if (node0 + r < n_nodes) {
            a = ((const float4*)accm)[(long long)(node0 + r) * 32 + c];
            b = ((const float4*)acch)[(long long)(node0 + r) * 32 + c];
        }
        *(float4*)&xm[r * PAD + c * 4] = a;
        *(float4*)&xh[r * PAD + c * 4] = b;
    }
    __syncthreads();

    float acc[8], acc2[8];

    // ---- layer 1 (main + hull) ----
    #pragma unroll
    for (int j = 0; j < 8; j++) { acc[j] = b1[o0 + j]; acc2[j] = b1h[o0 + j]; }
    for (int k = 0; k < 128; k += 4) {
        float4 xv = *(const float4*)&xm[ln * PAD + k];
        float4 hv = *(const float4*)&xh[ln * PAD + k];
        #pragma unroll
        for (int j = 0; j < 8; j++) {
            float4 w  = *(const float4*)&W1 [(o0 + j) * 128 + k];
            float4 wh = *(const float4*)&W1h[(o0 + j) * 128 + k];
            acc [j] += xv.x * w.x  + xv.y * w.y  + xv.z * w.z  + xv.w * w.w;
            acc2[j] += hv.x * wh.x + hv.y * wh.y + hv.z * wh.z + hv.w * wh.w;
        }
    }
    #pragma unroll
    for (int j = 0; j < 8; j++) {
        ym[ln * PAD + o0 + j] = ssp(acc[j]);
        yh[ln * PAD + o0 + j] = ssp(acc2[j]);
    }
    __syncthreads();

    // ---- layer 2 (main + hull), write cat into xm/xh (no longer read) ----
    #pragma unroll
    for (int j = 0; j < 8; j++) { acc[j] = b2[o0 + j]; acc2[j] = b2h[o0 + j]; }
    for (int k = 0; k < 128; k += 4) {
        float4 xv = *(const float4*)&ym[ln * PAD + k];
        float4 hv = *(const float4*)&yh[ln * PAD + k];
        #pragma unroll
        for (int j = 0; j < 8; j++) {
            float4 w  = *(const float4*)&W2 [(o0 + j) * 128 + k];
            float4 wh = *(const float4*)&W2h[(o0 + j) * 128 + k];
            acc [j] += xv.x * w.x  + xv.y * w.y  + xv.z * w.z  + xv.w * w.w;
            acc2[j] += hv.x * wh.x + hv.y * wh.y + hv.z * wh.z + hv.w * wh.w;
        }
    }
    #pragma unroll
    for (int j = 0; j < 8; j++) {
        xm[ln * PAD + o0 + j] = acc[j];
        xh[ln * PAD + o0 + j] = acc2[j];
    }
    __syncthreads();

    // ---- final layer: out = v + ssp(Wc * cat + bc) ----
    #pragma unroll
    for (int j = 0; j < 8; j++) acc[j] = bc[o0 + j];
    for (int k = 0; k < 128; k += 4) {
        float4 xv = *(const float4*)&xm[ln * PAD + k];
        float4 hv = *(const float4*)&xh[ln * PAD + k];
        #pragma unroll
        for (int j = 0; j < 8; j++) {
            float4 w  = *(const float4*)&Wc[(o0 + j) * 256 + k];
            float4 wh = *(const float4*)&Wc[(o0 + j) * 256 + 128 + k];
            acc[j] += xv.x * w.x  + xv.y * w.y  + xv.z * w.z  + xv.w * w.w;
            acc[j] += hv.x * wh.x + hv.y * wh.y + hv.z * wh.z + hv.w * wh.w;
        }
    }

    const int node = node0 + ln;
    if (node < n_nodes) {
        const float* vp = v   + (long long)node * 128 + o0;
        float*       op = out + (long long)node * 128 + o0;
        #pragma unroll
        for (int j = 0; j < 8; j++) op[j] = vp[j] + ssp(acc[j]);
    }
}

extern "C" void kernel_launch(void* const* d_in, const int* in_sizes, int n_in,
                              void* d_out, int out_size, void* d_ws, size_t ws_size,
                              hipStream_t stream)
{
    const float* v    = (const float*)d_in[0];
    const float* e    = (const float*)d_in[1];
    const int*   ei   = (const int*)  d_in[2];
    const float* eh   = (const float*)d_in[3];
    const int*   eih  = (const int*)  d_in[4];
    const float* W1   = (const float*)d_in[5];
    const float* b1   = (const float*)d_in[6];
    const float* W2   = (const float*)d_in[7];
    const float* b2   = (const float*)d_in[8];
    const float* W1h  = (const float*)d_in[9];
    const float* b1h  = (const float*)d_in[10];
    const float* W2h  = (const float*)d_in[11];
    const float* b2h  = (const float*)d_in[12];
    const float* Wc   = (const float*)d_in[13];
    const float* bc   = (const float*)d_in[14];
    float* out = (float*)d_out;

    const int       N  = in_sizes[0] / 128;
    const long long E  = in_sizes[1] / 128;
    const long long Eh = in_sizes[3] / 128;

    float* accm = (float*)d_ws;
    float* acch = accm + (size_t)N * 128;

    hipMemsetAsync(d_ws, 0, (size_t)N * 128 * 2 * sizeof(float), stream);

    const long long t4m = E * 32;
    scatter_kernel<<<(int)((t4m + 255) / 256), 256, 0, stream>>>(e, ei + E, accm, t4m);
    const long long t4h = Eh * 32;
    scatter_kernel<<<(int)((t4h + 255) / 256), 256, 0, stream>>>(eh, eih + Eh, acch, t4h);

    mlp_kernel<<<(N + 15) / 16, 256, 0, stream>>>(
        accm, acch, v, W1, b1, W2, b2, W1h, b1h, W2h, b2h, Wc, bc, out, N);
}

// Round 2
// 1813.181 us; speedup vs baseline: 2.5546x; 2.5546x over previous
//
#include <hip/hip_runtime.h>
#include <math.h>

// ssp(x) = softplus(x) - log(2), fast form: max(x,0) + log(1+exp(-|x|)) - log2
__device__ __forceinline__ float ssp(float x) {
    float ax = fabsf(x);
    return fmaxf(x, 0.0f) + __logf(1.0f + __expf(-ax)) - 0.69314718055994530942f;
}

// ---------------------------------------------------------------------------
// Fallback scatter-add (atomic), used only if ws_size too small for CSR path
// ---------------------------------------------------------------------------
__global__ __launch_bounds__(256) void scatter_kernel(
    const float* __restrict__ e, const int* __restrict__ tgt,
    float* __restrict__ acc, long long total4)
{
    long long i = (long long)blockIdx.x * 256 + threadIdx.x;
    if (i >= total4) return;
    int edge = (int)(i >> 5);
    int c4   = (int)(i & 31);
    int node = tgt[edge];
    float4 val = ((const float4*)e)[i];
    float* p = acc + (long long)node * 128 + c4 * 4;
    unsafeAtomicAdd(p + 0, val.x);
    unsafeAtomicAdd(p + 1, val.y);
    unsafeAtomicAdd(p + 2, val.z);
    unsafeAtomicAdd(p + 3, val.w);
}

// ---------------------------------------------------------------------------
// CSR build: histogram -> exclusive scan -> place edge ids
// ---------------------------------------------------------------------------
__global__ __launch_bounds__(256) void hist_kernel(
    const int* __restrict__ tgt, int* __restrict__ counts, int E)
{
    int i = blockIdx.x * 256 + threadIdx.x;
    if (i < E) atomicAdd(&counts[tgt[i]], 1);
}

__global__ __launch_bounds__(1024) void scan_kernel(
    const int* __restrict__ counts, int* __restrict__ offsets, int n)
{
    __shared__ int bufA[1024], bufB[1024];
    const int tid = threadIdx.x;
    int running = 0;
    for (int base = 0; base < n; base += 1024) {
        int idx = base + tid;
        int val = (idx < n) ? counts[idx] : 0;
        bufA[tid] = val;
        __syncthreads();
        int* src = bufA; int* dst = bufB;
        for (int off = 1; off < 1024; off <<= 1) {
            int x = src[tid];
            if (tid >= off) x += src[tid - off];
            dst[tid] = x;
            __syncthreads();
            int* t = src; src = dst; dst = t;
        }
        if (idx < n) offsets[idx] = running + src[tid] - val;  // exclusive
        int tot = src[1023];
        __syncthreads();
        running += tot;
    }
    if (tid == 0) offsets[n] = running;
}

__global__ __launch_bounds__(256) void place_kernel(
    const int* __restrict__ tgt, const int* __restrict__ offsets,
    int* __restrict__ cursors, int* __restrict__ perm, int E)
{
    int i = blockIdx.x * 256 + threadIdx.x;
    if (i < E) {
        int node = tgt[i];
        int pos = offsets[node] + atomicAdd(&cursors[node], 1);
        perm[pos] = i;
    }
}

// ---------------------------------------------------------------------------
// Gather: 32 lanes per node, each lane owns one float4 of the 128 channels.
// Edge rows are 512B contiguous -> fully coalesced random reads; one
// coalesced 512B write per node. Zero-degree nodes write zeros (no memset).
// ---------------------------------------------------------------------------
__global__ __launch_bounds__(256) void gather_kernel(
    const float* __restrict__ e, const int* __restrict__ perm,
    const int* __restrict__ offsets, float* __restrict__ acc, int n)
{
    int node = blockIdx.x * 8 + (threadIdx.x >> 5);
    if (node >= n) return;
    int c4 = threadIdx.x & 31;
    int s0 = offsets[node], s1 = offsets[node + 1];
    float4 s = make_float4(0.f, 0.f, 0.f, 0.f);
    int k = s0;
    for (; k + 2 <= s1; k += 2) {
        int e0 = perm[k], e1 = perm[k + 1];
        float4 a = ((const float4*)e)[(long long)e0 * 32 + c4];
        float4 b = ((const float4*)e)[(long long)e1 * 32 + c4];
        s.x += a.x; s.y += a.y; s.z += a.z; s.w += a.w;
        s.x += b.x; s.y += b.y; s.z += b.z; s.w += b.w;
    }
    if (k < s1) {
        float4 a = ((const float4*)e)[(long long)perm[k] * 32 + c4];
        s.x += a.x; s.y += a.y; s.z += a.z; s.w += a.w;
    }
    ((float4*)acc)[(long long)node * 32 + c4] = s;
}

// ---------------------------------------------------------------------------
// Fused MLP (unchanged structure from R0; ssp now uses fast exp/log)
// ---------------------------------------------------------------------------
#define PAD 132

__global__ __launch_bounds__(256) void mlp_kernel(
    const float* __restrict__ accm, const float* __restrict__ acch,
    const float* __restrict__ v,
    const float* __restrict__ W1,  const float* __restrict__ b1,
    const float* __restrict__ W2,  const float* __restrict__ b2,
    const float* __restrict__ W1h, const float* __restrict__ b1h,
    const float* __restrict__ W2h, const float* __restrict__ b2h,
    const float* __restrict__ Wc,  const float* __restrict__ bc,
    float* __restrict__ out, int n_nodes)
{
    __shared__ float xm[16 * PAD];
    __shared__ float xh[16 * PAD];
    __shared__ float ym[16 * PAD];
    __shared__ float yh[16 * PAD];

    const int tid = threadIdx.x;
    const int ln  = tid & 15;
    const int oc  = tid >> 4;
    const int o0  = oc * 8;
    const int node0 = blockIdx.x * 16;

    for (int p = tid; p < 512; p += 256) {
        int r = p >> 5, c = p & 31;
        float4 a = make_float4(0.f, 0.f, 0.f, 0.f);
        float4 b = make_float4(0.f, 0.f, 0.f, 0.f);
        if (node0 + r < n_nodes) {
            a = ((const float4*)accm)[(long long)(node0 + r) * 32 + c];
            b = ((const float4*)acch)[(long long)(node0 + r) * 32 + c];
        }
        *(float4*)&xm[r * PAD + c * 4] = a;
        *(float4*)&xh[r * PAD + c * 4] = b;
    }
    __syncthreads();

    float acc[8], acc2[8];

    #pragma unroll
    for (int j = 0; j < 8; j++) { acc[j] = b1[o0 + j]; acc2[j] = b1h[o0 + j]; }
    for (int k = 0; k < 128; k += 4) {
        float4 xv = *(const float4*)&xm[ln * PAD + k];
        float4 hv = *(const float4*)&xh[ln * PAD + k];
        #pragma unroll
        for (int j = 0; j < 8; j++) {
            float4 w  = *(const float4*)&W1 [(o0 + j) * 128 + k];
            float4 wh = *(const float4*)&W1h[(o0 + j) * 128 + k];
            acc [j] += xv.x * w.x  + xv.y * w.y  + xv.z * w.z  + xv.w * w.w;
            acc2[j] += hv.x * wh.x + hv.y * wh.y + hv.z * wh.z + hv.w * wh.w;
        }
    }
    #pragma unroll
    for (int j = 0; j < 8; j++) {
        ym[ln * PAD + o0 + j] = ssp(acc[j]);
        yh[ln * PAD + o0 + j] = ssp(acc2[j]);
    }
    __syncthreads();

    #pragma unroll
    for (int j = 0; j < 8; j++) { acc[j] = b2[o0 + j]; acc2[j] = b2h[o0 + j]; }
    for (int k = 0; k < 128; k += 4) {
        float4 xv = *(const float4*)&ym[ln * PAD + k];
        float4 hv = *(const float4*)&yh[ln * PAD + k];
        #pragma unroll
        for (int j = 0; j < 8; j++) {
            float4 w  = *(const float4*)&W2 [(o0 + j) * 128 + k];
            float4 wh = *(const float4*)&W2h[(o0 + j) * 128 + k];
            acc [j] += xv.x * w.x  + xv.y * w.y  + xv.z * w.z  + xv.w * w.w;
            acc2[j] += hv.x * wh.x + hv.y * wh.y + hv.z * wh.z + hv.w * wh.w;
        }
    }
    #pragma unroll
    for (int j = 0; j < 8; j++) {
        xm[ln * PAD + o0 + j] = acc[j];
        xh[ln * PAD + o0 + j] = acc2[j];
    }
    __syncthreads();

    #pragma unroll
    for (int j = 0; j < 8; j++) acc[j] = bc[o0 + j];
    for (int k = 0; k < 128; k += 4) {
        float4 xv = *(const float4*)&xm[ln * PAD + k];
        float4 hv = *(const float4*)&xh[ln * PAD + k];
        #pragma unroll
        for (int j = 0; j < 8; j++) {
            float4 w  = *(const float4*)&Wc[(o0 + j) * 256 + k];
            float4 wh = *(const float4*)&Wc[(o0 + j) * 256 + 128 + k];
            acc[j] += xv.x * w.x  + xv.y * w.y  + xv.z * w.z  + xv.w * w.w;
            acc[j] += hv.x * wh.x + hv.y * wh.y + hv.z * wh.z + hv.w * wh.w;
        }
    }

    const int node = node0 + ln;
    if (node < n_nodes) {
        const float* vp = v   + (long long)node * 128 + o0;
        float*       op = out + (long long)node * 128 + o0;
        #pragma unroll
        for (int j = 0; j < 8; j++) op[j] = vp[j] + ssp(acc[j]);
    }
}

extern "C" void kernel_launch(void* const* d_in, const int* in_sizes, int n_in,
                              void* d_out, int out_size, void* d_ws, size_t ws_size,
                              hipStream_t stream)
{
    const float* v    = (const float*)d_in[0];
    const float* e    = (const float*)d_in[1];
    const int*   ei   = (const int*)  d_in[2];
    const float* eh   = (const float*)d_in[3];
    const int*   eih  = (const int*)  d_in[4];
    const float* W1   = (const float*)d_in[5];
    const float* b1   = (const float*)d_in[6];
    const float* W2   = (const float*)d_in[7];
    const float* b2   = (const float*)d_in[8];
    const float* W1h  = (const float*)d_in[9];
    const float* b1h  = (const float*)d_in[10];
    const float* W2h  = (const float*)d_in[11];
    const float* b2h  = (const float*)d_in[12];
    const float* Wc   = (const float*)d_in[13];
    const float* bc   = (const float*)d_in[14];
    float* out = (float*)d_out;

    const int N  = in_sizes[0] / 128;
    const int E  = (int)(in_sizes[1] / 128);
    const int Eh = (int)(in_sizes[3] / 128);
    const int Emax = (E > Eh) ? E : Eh;

    // workspace layout
    float* accm = (float*)d_ws;
    float* acch = accm + (size_t)N * 128;
    int* counts  = (int*)(acch + (size_t)N * 128);
    int* offsets = counts + N;          // N+1 ints
    int* cursors = offsets + (N + 1);
    int* perm    = cursors + N;
    size_t need = ((size_t)N * 128 * 2) * 4 + ((size_t)3 * N + 1) * 4 + (size_t)Emax * 4;

    const int* tgt_m = ei  + E;   // edge_index row 1 = targets
    const int* tgt_h = eih + Eh;

    if (ws_size >= need) {
        // ---- CSR path: main edges ----
        hipMemsetAsync(counts, 0, (size_t)N * 4, stream);
        hipMemsetAsync(cursors, 0, (size_t)N * 4, stream);
        hist_kernel <<<(E + 255) / 256, 256, 0, stream>>>(tgt_m, counts, E);
        scan_kernel <<<1, 1024, 0, stream>>>(counts, offsets, N);
        place_kernel<<<(E + 255) / 256, 256, 0, stream>>>(tgt_m, offsets, cursors, perm, E);
        gather_kernel<<<(N + 7) / 8, 256, 0, stream>>>(e, perm, offsets, accm, N);

        // ---- CSR path: hull edges ----
        hipMemsetAsync(counts, 0, (size_t)N * 4, stream);
        hipMemsetAsync(cursors, 0, (size_t)N * 4, stream);
        hist_kernel <<<(Eh + 255) / 256, 256, 0, stream>>>(tgt_h, counts, Eh);
        scan_kernel <<<1, 1024, 0, stream>>>(counts, offsets, N);
        place_kernel<<<(Eh + 255) / 256, 256, 0, stream>>>(tgt_h, offsets, cursors, perm, Eh);
        gather_kernel<<<(N + 7) / 8, 256, 0, stream>>>(eh, perm, offsets, acch, N);
    } else {
        // ---- fallback: atomic scatter ----
        hipMemsetAsync(d_ws, 0, (size_t)N * 128 * 2 * sizeof(float), stream);
        const long long t4m = (long long)E * 32;
        scatter_kernel<<<(int)((t4m + 255) / 256), 256, 0, stream>>>(e, tgt_m, accm, t4m);
        const long long t4h = (long long)Eh * 32;
        scatter_kernel<<<(int)((t4h + 255) / 256), 256, 0, stream>>>(eh, tgt_h, acch, t4h);
    }

    mlp_kernel<<<(N + 15) / 16, 256, 0, stream>>>(
        accm, acch, v, W1, b1, W2, b2, W1h, b1h, W2h, b2h, Wc, bc, out, N);
}

// Round 3
// 653.273 us; speedup vs baseline: 7.0903x; 2.7755x over previous
//
#include <hip/hip_runtime.h>
#include <math.h>

typedef __attribute__((ext_vector_type(8))) short short8;
typedef __attribute__((ext_vector_type(4))) float f32x4;
typedef unsigned short u16;
typedef unsigned int u32;

// ssp(x) = softplus(x) - log(2), fast form
__device__ __forceinline__ float ssp(float x) {
    float ax = fabsf(x);
    return fmaxf(x, 0.0f) + __logf(1.0f + __expf(-ax)) - 0.69314718055994530942f;
}

// fp32 -> bf16 round-to-nearest-even
__device__ __forceinline__ u16 f2bf(float x) {
    u32 u = __float_as_uint(x);
    u32 r = (u + 0x7FFFu + ((u >> 16) & 1u)) >> 16;
    return (u16)r;
}

// ---------------------------------------------------------------------------
// CSR build: histogram -> parallel scan (3 kernels) -> place edge ids
// ---------------------------------------------------------------------------
__global__ __launch_bounds__(256) void hist_kernel(
    const int* __restrict__ tgt, int* __restrict__ counts, int E)
{
    int i = blockIdx.x * 256 + threadIdx.x;
    if (i < E) atomicAdd(&counts[tgt[i]], 1);
}

__global__ __launch_bounds__(1024) void scan1_kernel(
    const int* __restrict__ counts, int* __restrict__ offsets,
    int* __restrict__ bsums, int n)
{
    __shared__ int buf[2][1024];
    const int tid = threadIdx.x;
    const int idx = blockIdx.x * 1024 + tid;
    int val = (idx < n) ? counts[idx] : 0;
    int cur = 0;
    buf[0][tid] = val;
    __syncthreads();
    for (int off = 1; off < 1024; off <<= 1) {
        int x = buf[cur][tid];
        if (tid >= off) x += buf[cur][tid - off];
        buf[cur ^ 1][tid] = x;
        cur ^= 1;
        __syncthreads();
    }
    if (idx < n) offsets[idx] = buf[cur][tid] - val;   // block-local exclusive
    if (tid == 1023) bsums[blockIdx.x] = buf[cur][tid];
}

// nb <= 128 (N=100000 -> nb=98)
__global__ __launch_bounds__(128) void scan2_kernel(
    int* __restrict__ bsums, int nb, int* __restrict__ offsets, int n)
{
    __shared__ int b[2][128];
    const int tid = threadIdx.x;
    int val = (tid < nb) ? bsums[tid] : 0;
    int cur = 0;
    b[0][tid] = val;
    __syncthreads();
    for (int off = 1; off < 128; off <<= 1) {
        int x = b[cur][tid];
        if (tid >= off) x += b[cur][tid - off];
        b[cur ^ 1][tid] = x;
        cur ^= 1;
        __syncthreads();
    }
    if (tid < nb) bsums[tid] = b[cur][tid] - val;      // exclusive
    if (tid == 127) offsets[n] = b[cur][127];          // grand total
}

__global__ __launch_bounds__(256) void scan3_kernel(
    int* __restrict__ offsets, const int* __restrict__ bsums, int n)
{
    int idx = blockIdx.x * 256 + threadIdx.x;
    if (idx < n) offsets[idx] += bsums[idx >> 10];
}

__global__ __launch_bounds__(256) void place_kernel(
    const int* __restrict__ tgt, const int* __restrict__ offsets,
    int* __restrict__ cursors, int* __restrict__ perm, int E)
{
    int i = blockIdx.x * 256 + threadIdx.x;
    if (i < E) {
        int node = tgt[i];
        int pos = offsets[node] + atomicAdd(&cursors[node], 1);
        perm[pos] = i;
    }
}

// ---------------------------------------------------------------------------
// Gather: 32 lanes per node, lane owns one float4 of 128 channels; sums in
// fp32, writes bf16 (8B/lane coalesced).
// ---------------------------------------------------------------------------
__global__ __launch_bounds__(256) void gather_kernel(
    const float* __restrict__ e, const int* __restrict__ perm,
    const int* __restrict__ offsets, u16* __restrict__ acc, int n)
{
    int node = blockIdx.x * 8 + (threadIdx.x >> 5);
    if (node >= n) return;
    int c4 = threadIdx.x & 31;
    int s0 = offsets[node], s1 = offsets[node + 1];
    float4 s = make_float4(0.f, 0.f, 0.f, 0.f);
    int k = s0;
    for (; k + 2 <= s1; k += 2) {
        int e0 = perm[k], e1 = perm[k + 1];
        float4 a = ((const float4*)e)[(long long)e0 * 32 + c4];
        float4 b = ((const float4*)e)[(long long)e1 * 32 + c4];
        s.x += a.x; s.y += a.y; s.z += a.z; s.w += a.w;
        s.x += b.x; s.y += b.y; s.z += b.z; s.w += b.w;
    }
    if (k < s1) {
        float4 a = ((const float4*)e)[(long long)perm[k] * 32 + c4];
        s.x += a.x; s.y += a.y; s.z += a.z; s.w += a.w;
    }
    ushort4 o;
    o.x = f2bf(s.x); o.y = f2bf(s.y); o.z = f2bf(s.z); o.w = f2bf(s.w);
    *(ushort4*)&acc[(long long)node * 128 + c4 * 4] = o;
}

// ---------------------------------------------------------------------------
// Convert 5 weight matrices fp32 -> bf16 into ws: W1|W1h|W2|W2h|Wc  (98304)
// ---------------------------------------------------------------------------
__global__ __launch_bounds__(256) void wconvert_kernel(
    const float* __restrict__ W1, const float* __restrict__ W1h,
    const float* __restrict__ W2, const float* __restrict__ W2h,
    const float* __restrict__ Wc, u16* __restrict__ dst)
{
    int i = blockIdx.x * 256 + threadIdx.x;
    if (i >= 98304) return;
    const float* src; int off;
    if      (i < 16384) { src = W1;  off = i; }
    else if (i < 32768) { src = W1h; off = i - 16384; }
    else if (i < 49152) { src = W2;  off = i - 32768; }
    else if (i < 65536) { src = W2h; off = i - 49152; }
    else                { src = Wc;  off = i - 65536; }
    dst[i] = f2bf(src[off]);
}

// ---------------------------------------------------------------------------
// Fused 3-layer MLP via bf16 MFMA. Block = 64 nodes x 4 waves (256 thr).
// LDS tiles [64][128] bf16, XOR-swizzled in 16B chunks: chunk' = c ^ (row&7)
// so the 16-lane A-fragment column read (stride 256B) is conflict-free.
// MFMA 16x16x32 bf16; A-frag: lane l -> row l&15, k = (l>>4)*8+j;
// B-frag: col l&15, k = (l>>4)*8+j;  D: col l&15, row (l>>4)*4+r (m89).
// ---------------------------------------------------------------------------
#define MT 64

// ls indexed in 16B chunks (8 bf16); ch in [0,16)
#define CHUNK_IDX(row, ch) (((row) * 16 + ((ch) ^ ((row) & 7))))
#define AFRAG(ls, row, ch) (*(const short8*)&(ls)[CHUNK_IDX(row, ch) * 8])

__device__ __forceinline__ void layer128(
    const u16* __restrict__ ls, const u16* __restrict__ W,
    const float* __restrict__ bias, u16* __restrict__ dst,
    int rw, int lr, int kc, bool act)
{
    const int arow = rw + lr;
    short8 af[4];
    #pragma unroll
    for (int s = 0; s < 4; s++) af[s] = AFRAG(ls, arow, s * 4 + kc);
    #pragma unroll
    for (int nt = 0; nt < 8; nt++) {
        const int bcol = nt * 16 + lr;
        const short8* wr = (const short8*)(W + bcol * 128);
        f32x4 acc = {0.f, 0.f, 0.f, 0.f};
        #pragma unroll
        for (int s = 0; s < 4; s++)
            acc = __builtin_amdgcn_mfma_f32_16x16x32_bf16(af[s], wr[s * 4 + kc], acc, 0, 0, 0);
        const float bn = bias[bcol];
        #pragma unroll
        for (int r = 0; r < 4; r++) {
            const int drow = rw + kc * 4 + r;
            float val = acc[r] + bn;
            if (act) val = ssp(val);
            dst[CHUNK_IDX(drow, bcol >> 3) * 8 + (bcol & 7)] = f2bf(val);
        }
    }
}

__global__ __launch_bounds__(256) void mlp_mfma_kernel(
    const u16* __restrict__ accm, const u16* __restrict__ acch,
    const u16* __restrict__ Wbf,
    const float* __restrict__ b1, const float* __restrict__ b1h,
    const float* __restrict__ b2, const float* __restrict__ b2h,
    const float* __restrict__ bc,
    const float* __restrict__ v, float* __restrict__ out, int n)
{
    __shared__ __align__(16) u16 lsA[MT * 128];
    __shared__ __align__(16) u16 lsB[MT * 128];
    __shared__ __align__(16) u16 lsC[MT * 128];
    __shared__ __align__(16) u16 lsD[MT * 128];

    const int tid = threadIdx.x;
    const int l   = tid & 63;
    const int w   = tid >> 6;
    const int rw  = w * 16;
    const int lr  = l & 15;
    const int kc  = l >> 4;
    const int node0 = blockIdx.x * MT;

    const u16* W1  = Wbf;
    const u16* W1h = Wbf + 16384;
    const u16* W2  = Wbf + 32768;
    const u16* W2h = Wbf + 49152;
    const u16* Wc  = Wbf + 65536;

    // stage acc tiles (coalesced 16B loads, swizzled LDS writes)
    for (int p = tid; p < 1024; p += 256) {
        int row = p >> 4, c = p & 15;
        int4 a = make_int4(0, 0, 0, 0), b = a;
        if (node0 + row < n) {
            a = ((const int4*)accm)[(size_t)(node0 + row) * 16 + c];
            b = ((const int4*)acch)[(size_t)(node0 + row) * 16 + c];
        }
        ((int4*)lsA)[CHUNK_IDX(row, c)] = a;
        ((int4*)lsB)[CHUNK_IDX(row, c)] = b;
    }
    __syncthreads();

    // layer 1: h1 = ssp(x @ W1^T + b1)
    layer128(lsA, W1,  b1,  lsC, rw, lr, kc, true);
    layer128(lsB, W1h, b1h, lsD, rw, lr, kc, true);
    __syncthreads();

    // layer 2: z = h1 @ W2^T + b2   (overwrite lsA/lsB)
    layer128(lsC, W2,  b2,  lsA, rw, lr, kc, false);
    layer128(lsD, W2h, b2h, lsB, rw, lr, kc, false);
    __syncthreads();

    // final: out = v + ssp(cat(zm,zh) @ Wc^T + bc)
    {
        const int arow = rw + lr;
        short8 af[8];
        #pragma unroll
        for (int s = 0; s < 4; s++) af[s]     = AFRAG(lsA, arow, s * 4 + kc);
        #pragma unroll
        for (int s = 0; s < 4; s++) af[s + 4] = AFRAG(lsB, arow, s * 4 + kc);
        #pragma unroll
        for (int nt = 0; nt < 8; nt++) {
            const int bcol = nt * 16 + lr;
            const short8* wr = (const short8*)(Wc + bcol * 256);
            f32x4 acc = {0.f, 0.f, 0.f, 0.f};
            #pragma unroll
            for (int s = 0; s < 8; s++)
                acc = __builtin_amdgcn_mfma_f32_16x16x32_bf16(af[s], wr[s * 4 + kc], acc, 0, 0, 0);
            const float bn = bc[bcol];
            #pragma unroll
            for (int r = 0; r < 4; r++) {
                const int drow = rw + kc * 4 + r;
                const int node = node0 + drow;
                if (node < n) {
                    size_t off = (size_t)node * 128 + bcol;
                    out[off] = v[off] + ssp(acc[r] + bn);
                }
            }
        }
    }
}

extern "C" void kernel_launch(void* const* d_in, const int* in_sizes, int n_in,
                              void* d_out, int out_size, void* d_ws, size_t ws_size,
                              hipStream_t stream)
{
    const float* v    = (const float*)d_in[0];
    const float* e    = (const float*)d_in[1];
    const int*   ei   = (const int*)  d_in[2];
    const float* eh   = (const float*)d_in[3];
    const int*   eih  = (const int*)  d_in[4];
    const float* W1   = (const float*)d_in[5];
    const float* b1   = (const float*)d_in[6];
    const float* W2   = (const float*)d_in[7];
    const float* b2   = (const float*)d_in[8];
    const float* W1h  = (const float*)d_in[9];
    const float* b1h  = (const float*)d_in[10];
    const float* W2h  = (const float*)d_in[11];
    const float* b2h  = (const float*)d_in[12];
    const float* Wc   = (const float*)d_in[13];
    const float* bc   = (const float*)d_in[14];
    float* out = (float*)d_out;

    const int N  = in_sizes[0] / 128;
    const int E  = (int)(in_sizes[1] / 128);
    const int Eh = (int)(in_sizes[3] / 128);

    // workspace layout (all 16B-aligned)
    u16* accm = (u16*)d_ws;                      // N*128 bf16
    u16* acch = accm + (size_t)N * 128;          // N*128 bf16
    u16* Wbf  = acch + (size_t)N * 128;          // 98304 bf16
    int* counts  = (int*)(Wbf + 98304);          // N
    int* cursors = counts + N;                   // N
    int* offsets = cursors + N;                  // N+1
    int* bsums   = offsets + (N + 1);            // 128
    int* perm    = bsums + 128;                  // max(E, Eh)

    const int* tgt_m = ei  + E;
    const int* tgt_h = eih + Eh;

    const int NB = (N + 1023) / 1024;

    wconvert_kernel<<<(98304 + 255) / 256, 256, 0, stream>>>(W1, W1h, W2, W2h, Wc, Wbf);

    // ---- main edges ----
    hipMemsetAsync(counts, 0, (size_t)2 * N * 4, stream);
    hist_kernel <<<(E + 255) / 256, 256, 0, stream>>>(tgt_m, counts, E);
    scan1_kernel<<<NB, 1024, 0, stream>>>(counts, offsets, bsums, N);
    scan2_kernel<<<1, 128, 0, stream>>>(bsums, NB, offsets, N);
    scan3_kernel<<<(N + 255) / 256, 256, 0, stream>>>(offsets, bsums, N);
    place_kernel<<<(E + 255) / 256, 256, 0, stream>>>(tgt_m, offsets, cursors, perm, E);
    gather_kernel<<<(N + 7) / 8, 256, 0, stream>>>(e, perm, offsets, accm, N);

    // ---- hull edges ----
    hipMemsetAsync(counts, 0, (size_t)2 * N * 4, stream);
    hist_kernel <<<(Eh + 255) / 256, 256, 0, stream>>>(tgt_h, counts, Eh);
    scan1_kernel<<<NB, 1024, 0, stream>>>(counts, offsets, bsums, N);
    scan2_kernel<<<1, 128, 0, stream>>>(bsums, NB, offsets, N);
    scan3_kernel<<<(N + 255) / 256, 256, 0, stream>>>(offsets, bsums, N);
    place_kernel<<<(Eh + 255) / 256, 256, 0, stream>>>(tgt_h, offsets, cursors, perm, Eh);
    gather_kernel<<<(N + 7) / 8, 256, 0, stream>>>(eh, perm, offsets, acch, N);

    // ---- fused MLP ----
    mlp_mfma_kernel<<<(N + MT - 1) / MT, 256, 0, stream>>>(
        accm, acch, Wbf, b1, b1h, b2, b2h, bc, v, out, N);
}

// Round 5
// 613.688 us; speedup vs baseline: 7.5477x; 1.0645x over previous
//
#include <hip/hip_runtime.h>
#include <math.h>

typedef __attribute__((ext_vector_type(8))) short short8;
typedef __attribute__((ext_vector_type(4))) float f32x4;
typedef unsigned short u16;
typedef unsigned int u32;

// ssp(x) = softplus(x) - log(2), fast form
__device__ __forceinline__ float ssp(float x) {
    float ax = fabsf(x);
    return fmaxf(x, 0.0f) + __logf(1.0f + __expf(-ax)) - 0.69314718055994530942f;
}

// fp32 -> bf16 round-to-nearest-even
__device__ __forceinline__ u16 f2bf(float x) {
    u32 u = __float_as_uint(x);
    u32 r = (u + 0x7FFFu + ((u >> 16) & 1u)) >> 16;
    return (u16)r;
}

// ---------------------------------------------------------------------------
// Merged CSR build for BOTH edge sets: counts[2N] (main | hull)
// ---------------------------------------------------------------------------
__global__ __launch_bounds__(256) void hist2_kernel(
    const int* __restrict__ tgt_m, int E,
    const int* __restrict__ tgt_h, int Eh,
    int* __restrict__ counts, int N)
{
    int i = blockIdx.x * 256 + threadIdx.x;
    if (i < E) atomicAdd(&counts[tgt_m[i]], 1);
    else if (i < E + Eh) atomicAdd(&counts[N + tgt_h[i - E]], 1);
}

__global__ __launch_bounds__(1024) void scan1_kernel(
    const int* __restrict__ counts, int* __restrict__ offsets,
    int* __restrict__ bsums, int n)
{
    __shared__ int buf[2][1024];
    const int tid = threadIdx.x;
    const int idx = blockIdx.x * 1024 + tid;
    int val = (idx < n) ? counts[idx] : 0;
    int cur = 0;
    buf[0][tid] = val;
    __syncthreads();
    for (int off = 1; off < 1024; off <<= 1) {
        int x = buf[cur][tid];
        if (tid >= off) x += buf[cur][tid - off];
        buf[cur ^ 1][tid] = x;
        cur ^= 1;
        __syncthreads();
    }
    if (idx < n) offsets[idx] = buf[cur][tid] - val;   // block-local exclusive
    if (tid == 1023) bsums[blockIdx.x] = buf[cur][tid];
}

// nb <= 256 (2N=200000 -> nb=196)
__global__ __launch_bounds__(256) void scan2_kernel(
    int* __restrict__ bsums, int nb, int* __restrict__ offsets, int n)
{
    __shared__ int b[2][256];
    const int tid = threadIdx.x;
    int val = (tid < nb) ? bsums[tid] : 0;
    int cur = 0;
    b[0][tid] = val;
    __syncthreads();
    for (int off = 1; off < 256; off <<= 1) {
        int x = b[cur][tid];
        if (tid >= off) x += b[cur][tid - off];
        b[cur ^ 1][tid] = x;
        cur ^= 1;
        __syncthreads();
    }
    if (tid < nb) bsums[tid] = b[cur][tid] - val;      // exclusive
    if (tid == 255) offsets[n] = b[cur][255];          // grand total
}

__global__ __launch_bounds__(256) void scan3_kernel(
    int* __restrict__ offsets, const int* __restrict__ bsums, int n)
{
    int idx = blockIdx.x * 256 + threadIdx.x;
    if (idx < n) offsets[idx] += bsums[idx >> 10];
}

__global__ __launch_bounds__(256) void place2_kernel(
    const int* __restrict__ tgt_m, int E,
    const int* __restrict__ tgt_h, int Eh,
    const int* __restrict__ offsets, int* __restrict__ cursors,
    int* __restrict__ perm, int N)
{
    int i = blockIdx.x * 256 + threadIdx.x;
    if (i < E) {
        int slot = tgt_m[i];
        int pos = offsets[slot] + atomicAdd(&cursors[slot], 1);
        perm[pos] = i;                      // main edge id
    } else if (i < E + Eh) {
        int slot = N + tgt_h[i - E];
        int pos = offsets[slot] + atomicAdd(&cursors[slot], 1);
        perm[pos] = i - E;                  // hull-local edge id
    }
}

// ---------------------------------------------------------------------------
// Gather (both sets): 32 lanes per node-slot; slot<N -> main, else hull.
// 4 edge rows in flight per half-wave; nontemporal loads on streamed e rows
// (via clang ext_vector f32x4 — __builtin_nontemporal_load rejects the
// HIP_vector_type float4 struct).
// ---------------------------------------------------------------------------
__global__ __launch_bounds__(256) void gather_kernel(
    const float* __restrict__ e, const float* __restrict__ eh,
    const int* __restrict__ perm, const int* __restrict__ offsets,
    u16* __restrict__ accm, u16* __restrict__ acch, int n)
{
    int slot = blockIdx.x * 8 + (threadIdx.x >> 5);
    if (slot >= 2 * n) return;
    const int c4 = threadIdx.x & 31;
    const bool hull = slot >= n;
    const f32x4* src = (const f32x4*)(hull ? eh : e);
    const int node = hull ? slot - n : slot;
    u16* dst = hull ? acch : accm;

    int s0 = offsets[slot], s1 = offsets[slot + 1];
    f32x4 s = {0.f, 0.f, 0.f, 0.f};
    int k = s0;
    for (; k + 4 <= s1; k += 4) {
        int p0 = perm[k], p1 = perm[k + 1], p2 = perm[k + 2], p3 = perm[k + 3];
        f32x4 a = __builtin_nontemporal_load(&src[(size_t)p0 * 32 + c4]);
        f32x4 b = __builtin_nontemporal_load(&src[(size_t)p1 * 32 + c4]);
        f32x4 c = __builtin_nontemporal_load(&src[(size_t)p2 * 32 + c4]);
        f32x4 d = __builtin_nontemporal_load(&src[(size_t)p3 * 32 + c4]);
        s += a + b + c + d;
    }
    for (; k + 2 <= s1; k += 2) {
        int p0 = perm[k], p1 = perm[k + 1];
        f32x4 a = __builtin_nontemporal_load(&src[(size_t)p0 * 32 + c4]);
        f32x4 b = __builtin_nontemporal_load(&src[(size_t)p1 * 32 + c4]);
        s += a + b;
    }
    if (k < s1) {
        f32x4 a = __builtin_nontemporal_load(&src[(size_t)perm[k] * 32 + c4]);
        s += a;
    }
    ushort4 o;
    o.x = f2bf(s.x); o.y = f2bf(s.y); o.z = f2bf(s.z); o.w = f2bf(s.w);
    *(ushort4*)&dst[(size_t)node * 128 + c4 * 4] = o;
}

// ---------------------------------------------------------------------------
// Convert 5 weight matrices fp32 -> bf16 into ws: W1|W1h|W2|W2h|Wc  (98304)
// ---------------------------------------------------------------------------
__global__ __launch_bounds__(256) void wconvert_kernel(
    const float* __restrict__ W1, const float* __restrict__ W1h,
    const float* __restrict__ W2, const float* __restrict__ W2h,
    const float* __restrict__ Wc, u16* __restrict__ dst)
{
    int i = blockIdx.x * 256 + threadIdx.x;
    if (i >= 98304) return;
    const float* src; int off;
    if      (i < 16384) { src = W1;  off = i; }
    else if (i < 32768) { src = W1h; off = i - 16384; }
    else if (i < 49152) { src = W2;  off = i - 32768; }
    else if (i < 65536) { src = W2h; off = i - 49152; }
    else                { src = Wc;  off = i - 65536; }
    dst[i] = f2bf(src[off]);
}

// ---------------------------------------------------------------------------
// Fused 3-layer MLP via bf16 MFMA. Block = 64 nodes x 4 waves (256 thr).
// LDS tiles [64][128] bf16, XOR chunk-swizzle: chunk' = c ^ (row&7).
// MFMA 16x16x32 bf16; D layout: col=lane&15, row=(lane>>4)*4+r (m89).
// ---------------------------------------------------------------------------
#define MT 64

#define CHUNK_IDX(row, ch) (((row) * 16 + ((ch) ^ ((row) & 7))))
#define AFRAG(ls, row, ch) (*(const short8*)&(ls)[CHUNK_IDX(row, ch) * 8])

__device__ __forceinline__ void layer128(
    const u16* __restrict__ ls, const u16* __restrict__ W,
    const float* __restrict__ bias, u16* __restrict__ dst,
    int rw, int lr, int kc, bool act)
{
    const int arow = rw + lr;
    short8 af[4];
    #pragma unroll
    for (int s = 0; s < 4; s++) af[s] = AFRAG(ls, arow, s * 4 + kc);
    #pragma unroll
    for (int nt = 0; nt < 8; nt++) {
        const int bcol = nt * 16 + lr;
        const short8* wr = (const short8*)(W + bcol * 128);
        f32x4 acc = {0.f, 0.f, 0.f, 0.f};
        #pragma unroll
        for (int s = 0; s < 4; s++)
            acc = __builtin_amdgcn_mfma_f32_16x16x32_bf16(af[s], wr[s * 4 + kc], acc, 0, 0, 0);
        const float bn = bias[bcol];
        #pragma unroll
        for (int r = 0; r < 4; r++) {
            const int drow = rw + kc * 4 + r;
            float val = acc[r] + bn;
            if (act) val = ssp(val);
            dst[CHUNK_IDX(drow, bcol >> 3) * 8 + (bcol & 7)] = f2bf(val);
        }
    }
}

__global__ __launch_bounds__(256) void mlp_mfma_kernel(
    const u16* __restrict__ accm, const u16* __restrict__ acch,
    const u16* __restrict__ Wbf,
    const float* __restrict__ b1, const float* __restrict__ b1h,
    const float* __restrict__ b2, const float* __restrict__ b2h,
    const float* __restrict__ bc,
    const float* __restrict__ v, float* __restrict__ out, int n)
{
    __shared__ __align__(16) u16 lsA[MT * 128];
    __shared__ __align__(16) u16 lsB[MT * 128];
    __shared__ __align__(16) u16 lsC[MT * 128];
    __shared__ __align__(16) u16 lsD[MT * 128];

    const int tid = threadIdx.x;
    const int l   = tid & 63;
    const int w   = tid >> 6;
    const int rw  = w * 16;
    const int lr  = l & 15;
    const int kc  = l >> 4;
    const int node0 = blockIdx.x * MT;

    const u16* W1  = Wbf;
    const u16* W1h = Wbf + 16384;
    const u16* W2  = Wbf + 32768;
    const u16* W2h = Wbf + 49152;
    const u16* Wc  = Wbf + 65536;

    for (int p = tid; p < 1024; p += 256) {
        int row = p >> 4, c = p & 15;
        int4 a = make_int4(0, 0, 0, 0), b = a;
        if (node0 + row < n) {
            a = ((const int4*)accm)[(size_t)(node0 + row) * 16 + c];
            b = ((const int4*)acch)[(size_t)(node0 + row) * 16 + c];
        }
        ((int4*)lsA)[CHUNK_IDX(row, c)] = a;
        ((int4*)lsB)[CHUNK_IDX(row, c)] = b;
    }
    __syncthreads();

    layer128(lsA, W1,  b1,  lsC, rw, lr, kc, true);
    layer128(lsB, W1h, b1h, lsD, rw, lr, kc, true);
    __syncthreads();

    layer128(lsC, W2,  b2,  lsA, rw, lr, kc, false);
    layer128(lsD, W2h, b2h, lsB, rw, lr, kc, false);
    __syncthreads();

    {
        const int arow = rw + lr;
        short8 af[8];
        #pragma unroll
        for (int s = 0; s < 4; s++) af[s]     = AFRAG(lsA, arow, s * 4 + kc);
        #pragma unroll
        for (int s = 0; s < 4; s++) af[s + 4] = AFRAG(lsB, arow, s * 4 + kc);
        #pragma unroll
        for (int nt = 0; nt < 8; nt++) {
            const int bcol = nt * 16 + lr;
            const short8* wr = (const short8*)(Wc + bcol * 256);
            f32x4 acc = {0.f, 0.f, 0.f, 0.f};
            #pragma unroll
            for (int s = 0; s < 8; s++)
                acc = __builtin_amdgcn_mfma_f32_16x16x32_bf16(af[s], wr[s * 4 + kc], acc, 0, 0, 0);
            const float bn = bc[bcol];
            #pragma unroll
            for (int r = 0; r < 4; r++) {
                const int drow = rw + kc * 4 + r;
                const int node = node0 + drow;
                if (node < n) {
                    size_t off = (size_t)node * 128 + bcol;
                    out[off] = v[off] + ssp(acc[r] + bn);
                }
            }
        }
    }
}

extern "C" void kernel_launch(void* const* d_in, const int* in_sizes, int n_in,
                              void* d_out, int out_size, void* d_ws, size_t ws_size,
                              hipStream_t stream)
{
    const float* v    = (const float*)d_in[0];
    const float* e    = (const float*)d_in[1];
    const int*   ei   = (const int*)  d_in[2];
    const float* eh   = (const float*)d_in[3];
    const int*   eih  = (const int*)  d_in[4];
    const float* W1   = (const float*)d_in[5];
    const float* b1   = (const float*)d_in[6];
    const float* W2   = (const float*)d_in[7];
    const float* b2   = (const float*)d_in[8];
    const float* W1h  = (const float*)d_in[9];
    const float* b1h  = (const float*)d_in[10];
    const float* W2h  = (const float*)d_in[11];
    const float* b2h  = (const float*)d_in[12];
    const float* Wc   = (const float*)d_in[13];
    const float* bc   = (const float*)d_in[14];
    float* out = (float*)d_out;

    const int N  = in_sizes[0] / 128;
    const int E  = (int)(in_sizes[1] / 128);
    const int Eh = (int)(in_sizes[3] / 128);
    const int n2 = 2 * N;

    // workspace layout (all 16B-aligned)
    u16* accm = (u16*)d_ws;                      // N*128 bf16
    u16* acch = accm + (size_t)N * 128;          // N*128 bf16
    u16* Wbf  = acch + (size_t)N * 128;          // 98304 bf16
    int* counts  = (int*)(Wbf + 98304);          // 2N
    int* cursors = counts + n2;                  // 2N (contiguous with counts)
    int* offsets = cursors + n2;                 // 2N+1
    int* bsums   = offsets + (n2 + 1);           // 256
    int* perm    = bsums + 256;                  // E + Eh

    const int* tgt_m = ei  + E;   // edge_index row 1 = targets
    const int* tgt_h = eih + Eh;

    const int NB  = (n2 + 1023) / 1024;
    const int ET  = E + Eh;

    wconvert_kernel<<<(98304 + 255) / 256, 256, 0, stream>>>(W1, W1h, W2, W2h, Wc, Wbf);

    (void)hipMemsetAsync(counts, 0, (size_t)2 * n2 * 4, stream);   // counts + cursors
    hist2_kernel <<<(ET + 255) / 256, 256, 0, stream>>>(tgt_m, E, tgt_h, Eh, counts, N);
    scan1_kernel <<<NB, 1024, 0, stream>>>(counts, offsets, bsums, n2);
    scan2_kernel <<<1, 256, 0, stream>>>(bsums, NB, offsets, n2);
    scan3_kernel <<<(n2 + 255) / 256, 256, 0, stream>>>(offsets, bsums, n2);
    place2_kernel<<<(ET + 255) / 256, 256, 0, stream>>>(tgt_m, E, tgt_h, Eh, offsets, cursors, perm, N);
    gather_kernel<<<(n2 + 7) / 8, 256, 0, stream>>>(e, eh, perm, offsets, accm, acch, N);

    mlp_mfma_kernel<<<(N + MT - 1) / MT, 256, 0, stream>>>(
        accm, acch, Wbf, b1, b1h, b2, b2h, bc, v, out, N);
}